// Round 17
// baseline (174.386 us; speedup 1.0000x reference)
//
#include <hip/hip_runtime.h>
#include <hip/hip_fp16.h>
#include <math.h>

// SGC: out = log_softmax( S^3 * x * (W1*W2*W3) )
// Pipeline: w12 -> wc -> FUSED{gemm || bucket-partition} -> bucket-local CSR
// (+ degree histogram) -> degree-sort work items -> 3x gather-agg
// (12 nodes/wave, 5-lane groups, uint4 f16 loads, v_pk_add_f16, 10-edge
// unroll w/ dual accumulators, pipelined indices, degree-balanced waves).
// NOTE: all __shfl are executed UNCONDITIONALLY by all 64 lanes.

#define BW    128     // nodes per bucket
#define NBMAX 1024
#define BCAP  3072    // per-bucket capacity (avg 2046, +22 sigma slack)
#define D     40
#define RS    64      // padded row stride (f16 elems) = 128 B (one L2 line)
#define NPW   12      // nodes per wave in k_agg
#define PCHUNK 4096   // edges per partition block
#define DBINS 128     // degree-sort bins

typedef unsigned short u16;
typedef unsigned int   u32;

static __device__ inline u32 hadd2u(u32 a, u32 b) {
    __half2 ha = *(__half2*)&a, hb = *(__half2*)&b;
    __half2 r = __hadd2(ha, hb);
    return *(u32*)&r;
}

// ---------- weight collapse, multi-block ----------
// W12 = W1(128x64) @ W2(64x64); block 0 also zeroes gcnt + dcnt
__global__ void k_w12(const float* __restrict__ W1, const float* __restrict__ W2,
                      float* __restrict__ W12, int* __restrict__ gcnt,
                      int* __restrict__ dcnt) {
    int idx = blockIdx.x * blockDim.x + threadIdx.x;
    if (blockIdx.x == 0) {
        for (int i = threadIdx.x; i < NBMAX; i += blockDim.x) gcnt[i] = 0;
        if (threadIdx.x < DBINS) dcnt[threadIdx.x] = 0;
    }
    if (idx >= 128 * 64) return;
    int r = idx >> 6, c = idx & 63;
    float acc = 0.f;
#pragma unroll
    for (int k = 0; k < 64; ++k) acc += W1[r * 64 + k] * W2[k * 64 + c];
    W12[idx] = acc;
}

// Wc = W12(128x64) @ W3(64x40)
__global__ void k_wc(const float* __restrict__ W12, const float* __restrict__ W3,
                     float* __restrict__ Wc) {
    int idx = blockIdx.x * blockDim.x + threadIdx.x;
    if (idx >= 128 * 40) return;
    int r = idx / 40, c = idx - r * 40;
    float acc = 0.f;
#pragma unroll
    for (int k = 0; k < 64; ++k) acc += W12[r * 64 + k] * W3[k * 40 + c];
    Wc[idx] = acc;
}

// ---------- FUSED: blocks [0,npart) partition edges; rest do the GEMM ------
__global__ void k_gp(const float4* __restrict__ x4, const float4* __restrict__ Wc4,
                     u16* __restrict__ yout, int n_nodes,
                     const int* __restrict__ src, const int* __restrict__ dst,
                     int* __restrict__ gcnt, int* __restrict__ part,
                     int E, int nb, int npart) {
    __shared__ union {
        struct { int h[NBMAX]; int base[NBMAX]; } p;
        float4 wc[1280];
    } sm;
    int t = threadIdx.x;

    if ((int)blockIdx.x < npart) {
        // ---------------- partition path ----------------
        int e0 = blockIdx.x * PCHUNK;
        int e1 = min(e0 + PCHUNK, E);
        for (int i = t; i < nb; i += 256) sm.p.h[i] = 0;
        __syncthreads();
        for (int e = e0 + t; e < e1; e += 1024) {
#pragma unroll
            for (int u = 0; u < 4; ++u) {
                int ee = e + u * 256;
                if (ee < e1) atomicAdd(&sm.p.h[dst[ee] >> 7], 1);
            }
        }
        __syncthreads();
        for (int i = t; i < nb; i += 256) {
            int c = sm.p.h[i];
            sm.p.base[i] = c ? atomicAdd(&gcnt[i], c) : 0;
        }
        __syncthreads();
        for (int i = t; i < nb; i += 256) sm.p.h[i] = 0;  // reuse as cursor
        __syncthreads();
        for (int eb = e0 + t; eb < e1; eb += 2048) {
            int dd[8], ss[8], pp[8];
#pragma unroll
            for (int u = 0; u < 8; ++u) {
                int e = eb + u * 256;
                bool v = e < e1;
                dd[u] = v ? dst[e] : 0;
                ss[u] = v ? src[e] : 0;
            }
#pragma unroll
            for (int u = 0; u < 8; ++u) {
                int e = eb + u * 256;
                int b = dd[u] >> 7;
                pp[u] = (e < e1) ? (sm.p.base[b] + atomicAdd(&sm.p.h[b], 1)) : BCAP;
            }
#pragma unroll
            for (int u = 0; u < 8; ++u) {
                int b = dd[u] >> 7;
                if (pp[u] < BCAP)
                    part[(size_t)b * BCAP + pp[u]] = (ss[u] << 7) | (dd[u] & 127);
            }
        }
    } else {
        // ---------------- gemm path ----------------
        for (int i = t; i < 1280; i += 256) sm.wc[i] = Wc4[i];
        __syncthreads();
        int tid = ((int)blockIdx.x - npart) * 256 + t;
        int node = tid / 5, j0 = tid - node * 5;
        if (node >= n_nodes) return;
        float4 a0 = {0.f, 0.f, 0.f, 0.f}, a1 = {0.f, 0.f, 0.f, 0.f};
        const float4* xr = x4 + (size_t)node * 32;
#pragma unroll
        for (int k4 = 0; k4 < 32; ++k4) {
            float4 v = xr[k4];
#pragma unroll
            for (int kk = 0; kk < 4; ++kk) {
                float c = (kk == 0) ? v.x : (kk == 1) ? v.y : (kk == 2) ? v.z : v.w;
                float4 w0 = sm.wc[(k4 * 4 + kk) * 10 + j0 * 2];
                float4 w1 = sm.wc[(k4 * 4 + kk) * 10 + j0 * 2 + 1];
                a0.x += c * w0.x; a0.y += c * w0.y; a0.z += c * w0.z; a0.w += c * w0.w;
                a1.x += c * w1.x; a1.y += c * w1.y; a1.z += c * w1.z; a1.w += c * w1.w;
            }
        }
        __half2 h0 = __floats2half2_rn(a0.x, a0.y);
        __half2 h1 = __floats2half2_rn(a0.z, a0.w);
        __half2 h2 = __floats2half2_rn(a1.x, a1.y);
        __half2 h3 = __floats2half2_rn(a1.z, a1.w);
        uint4 st;
        st.x = *(u32*)&h0; st.y = *(u32*)&h1; st.z = *(u32*)&h2; st.w = *(u32*)&h3;
        *(uint4*)(yout + (size_t)node * RS + j0 * 8) = st;
    }
}

// ---------- bucket-local CSR + degree histogram ----------
__global__ void k_csr(const int* __restrict__ part, const int* __restrict__ gcnt,
                      int2* __restrict__ offs2, int* __restrict__ ssort,
                      int* __restrict__ dcnt, int N) {
    __shared__ int cnt[BW];
    __shared__ int pos[BW];
    __shared__ int cur[BW];
    __shared__ int wsum[2];
    __shared__ int dh[DBINS];
    int b = blockIdx.x, t = threadIdx.x;
    int m = min(gcnt[b], BCAP);
    const int* bp = part + (size_t)b * BCAP;
    if (t < BW) cnt[t] = 0;
    if (t >= BW && t < BW + DBINS) dh[t - BW] = 0;
    __syncthreads();
    for (int k = t; k < m; k += 256)
        atomicAdd(&cnt[bp[k] & 127], 1);
    __syncthreads();
    int v = 0, inc = 0;
    if (t < BW) {
        v = cnt[t];
        inc = v;
#pragma unroll
        for (int off = 1; off < 64; off <<= 1) {
            int u = __shfl_up(inc, off, 64);
            if ((t & 63) >= off) inc += u;
        }
        if ((t & 63) == 63) wsum[t >> 6] = inc;
    }
    __syncthreads();
    int node0 = b * BW;
    if (t < BW) {
        int local = ((t >= 64) ? wsum[0] : 0) + inc - v;   // exclusive
        pos[t] = local;
        cur[t] = 0;
        if (node0 + t < N) {
            offs2[node0 + t] = make_int2(b * BCAP + local, b * BCAP + local + v);
            atomicAdd(&dh[min(v, DBINS - 1)], 1);
        }
    }
    __syncthreads();
    if (t < DBINS && dh[t]) atomicAdd(&dcnt[t], dh[t]);
    for (int k = t; k < m; k += 256) {
        int p = bp[k];
        int r = p & 127;
        int loc = atomicAdd(&cur[r], 1);
        ssort[(size_t)b * BCAP + pos[r] + loc] = p >> 7;
    }
}

// ---------- degree-bin exclusive scan (1 block) ----------
__global__ void k_dscan(const int* __restrict__ dcnt, int* __restrict__ dcur) {
    __shared__ int sh[DBINS];
    int t = threadIdx.x;
    int v = dcnt[t];
    sh[t] = v;
    __syncthreads();
    for (int off = 1; off < DBINS; off <<= 1) {
        int u = (t >= off) ? sh[t - off] : 0;
        __syncthreads();
        sh[t] += u;
        __syncthreads();
    }
    dcur[t] = sh[t] - v;
}

// ---------- scatter nodes into degree-sorted work arrays ----------
__global__ void k_dscat(const int2* __restrict__ offs2, int* __restrict__ dcur,
                        int2* __restrict__ sbe, int* __restrict__ snode, int N) {
    __shared__ int h[DBINS];
    __shared__ int base[DBINS];
    int t = threadIdx.x;
    int n0 = blockIdx.x * 1024;
    int n1 = min(n0 + 1024, N);
    if (t < DBINS) h[t] = 0;
    __syncthreads();
    int2 be[4]; int bin[4];
#pragma unroll
    for (int u = 0; u < 4; ++u) {
        int n = n0 + t + u * 256;
        bin[u] = -1;
        if (n < n1) {
            be[u] = offs2[n];
            bin[u] = min(be[u].y - be[u].x, DBINS - 1);
            atomicAdd(&h[bin[u]], 1);
        }
    }
    __syncthreads();
    if (t < DBINS) {
        int c = h[t];
        base[t] = c ? atomicAdd(&dcur[t], c) : 0;
        h[t] = 0;
    }
    __syncthreads();
#pragma unroll
    for (int u = 0; u < 4; ++u) {
        if (bin[u] >= 0) {
            int p = base[bin[u]] + atomicAdd(&h[bin[u]], 1);
            sbe[p] = be[u];
            snode[p] = n0 + t + u * 256;
        }
    }
}

// ---------- aggregation: 12 work items per wave, 5-lane group per item -----
// Work items are degree-sorted -> mdeg ~= deg for every group in the wave.
template <int FINAL>
__global__ void k_agg(const u16* __restrict__ yin, void* __restrict__ youtv,
                      const int2* __restrict__ sbe, const int* __restrict__ snode,
                      const int* __restrict__ srcs, int n_nodes) {
    int wid = (blockIdx.x * blockDim.x + threadIdx.x) >> 6;
    int lane = threadIdx.x & 63;
    int g = lane / 5;                 // 0..12 (lanes 60..63: g=12, idle)
    int sub = lane - g * 5;           // 0..4
    int item = wid * NPW + g;
    bool nv = (g < NPW) && (item < n_nodes);
    int cl = nv ? item : 0;
    int2 be = sbe[cl];
    int node = snode[cl];
    int beg = be.x;
    int deg = nv ? (be.y - be.x) : 0;
    u32 suboff = (u32)sub * 16u;      // byte offset within 128B row
    u32 c0 = 0, c1 = 0, c2 = 0, c3 = 0;   // accumulator set A
    u32 d0 = 0, d1 = 0, d2 = 0, d3 = 0;   // accumulator set B
    // wave-uniform max degree (sorted -> tight)
    int mdeg = deg;
#pragma unroll
    for (int off = 1; off < 64; off <<= 1)
        mdeg = max(mdeg, __shfl_xor(mdeg, off, 64));
    // prologue: index blocks for k=0..9
    int sv0 = (sub < deg) ? srcs[beg + sub] : 0;
    int sv1 = (5 + sub < deg) ? srcs[beg + 5 + sub] : 0;
    for (int k = 0; k < mdeg; k += 10) {
        int kn = k + 10;
        int svn0 = (kn + sub < deg) ? srcs[beg + kn + sub] : 0;
        int svn1 = (kn + 5 + sub < deg) ? srcs[beg + kn + 5 + sub] : 0;
#pragma unroll
        for (int j = 0; j < 5; ++j) {
            int s = __shfl(sv0, g * 5 + j, 64);   // ALL lanes execute
            if (k + j < deg) {
                uint4 w = *(const uint4*)((const char*)yin +
                              (size_t)(((u32)s << 7) + suboff));
                c0 = hadd2u(c0, w.x); c1 = hadd2u(c1, w.y);
                c2 = hadd2u(c2, w.z); c3 = hadd2u(c3, w.w);
            }
        }
#pragma unroll
        for (int j = 0; j < 5; ++j) {
            int s = __shfl(sv1, g * 5 + j, 64);   // ALL lanes execute
            if (k + 5 + j < deg) {
                uint4 w = *(const uint4*)((const char*)yin +
                              (size_t)(((u32)s << 7) + suboff));
                d0 = hadd2u(d0, w.x); d1 = hadd2u(d1, w.y);
                d2 = hadd2u(d2, w.z); d3 = hadd2u(d3, w.w);
            }
        }
        sv0 = svn0; sv1 = svn1;
    }
    c0 = hadd2u(c0, d0); c1 = hadd2u(c1, d1);
    c2 = hadd2u(c2, d2); c3 = hadd2u(c3, d3);
    if (FINAL) {
        float2 f0 = __half22float2(*(__half2*)&c0);
        float2 f1 = __half22float2(*(__half2*)&c1);
        float2 f2 = __half22float2(*(__half2*)&c2);
        float2 f3 = __half22float2(*(__half2*)&c3);
        // group-local (5-lane) reduce: rotate +1,+2 on partials, +4 on orig
        int s1 = sub + 1; s1 = (s1 >= 5) ? s1 - 5 : s1;
        int s2 = sub + 2; s2 = (s2 >= 5) ? s2 - 5 : s2;
        int s4 = sub + 4; s4 = (s4 >= 5) ? s4 - 5 : s4;
        int r1 = g * 5 + s1, r2 = g * 5 + s2, r4 = g * 5 + s4;
        float m0 = fmaxf(fmaxf(fmaxf(f0.x, f0.y), fmaxf(f1.x, f1.y)),
                         fmaxf(fmaxf(f2.x, f2.y), fmaxf(f3.x, f3.y)));
        float m = fmaxf(m0, __shfl(m0, r1, 64));        // window 2
        m = fmaxf(m, __shfl(m, r2, 64));                // window 4
        m = fmaxf(m, __shfl(m0, r4, 64));               // + elem at +4
        float e0 = __expf(f0.x - m) + __expf(f0.y - m) + __expf(f1.x - m) +
                   __expf(f1.y - m) + __expf(f2.x - m) + __expf(f2.y - m) +
                   __expf(f3.x - m) + __expf(f3.y - m);
        float sm = e0 + __shfl(e0, r1, 64);             // window 2
        sm = sm + __shfl(sm, r2, 64);                   // window 4
        sm = sm + __shfl(e0, r4, 64);                   // + elem at +4
        float ls = __logf(sm) + m;
        if (nv) {
            float4 o1 = {f0.x - ls, f0.y - ls, f1.x - ls, f1.y - ls};
            float4 o2 = {f2.x - ls, f2.y - ls, f3.x - ls, f3.y - ls};
            float* op = (float*)youtv + (size_t)node * D + sub * 8;
            *(float4*)op = o1;
            *(float4*)(op + 4) = o2;
        }
    } else {
        if (nv) {
            uint4 st = {c0, c1, c2, c3};
            *(uint4*)((u16*)youtv + (size_t)node * RS + sub * 8) = st;
        }
    }
}

extern "C" void kernel_launch(void* const* d_in, const int* in_sizes, int n_in,
                              void* d_out, int out_size, void* d_ws, size_t ws_size,
                              hipStream_t stream) {
    const float* x   = (const float*)d_in[0];
    const int* esrc  = (const int*)d_in[1];
    const int* edst  = (const int*)d_in[2];
    const float* W1  = (const float*)d_in[3];
    const float* W2  = (const float*)d_in[4];
    const float* W3  = (const float*)d_in[5];
    int N = in_sizes[0] / 128;
    int E = in_sizes[1];
    float* out = (float*)d_out;

    int nb = (N + BW - 1) / BW;

    char* ws = (char*)d_ws;
    auto alloc = [&](size_t bytes) {
        char* p = ws;
        ws += (bytes + 255) & ~(size_t)255;
        return p;
    };
    u16* bufA   = (u16*)alloc((size_t)N * RS * sizeof(u16));        // 12.8 MB
    u16* bufB   = (u16*)alloc((size_t)N * RS * sizeof(u16));        // 12.8 MB
    int* part   = (int*)bufB;   // alias: part dead before bufB first written
    int* ssort  = (int*)alloc((size_t)nb * BCAP * sizeof(int));     // 9.6 MB
    int2* offs2 = (int2*)alloc((size_t)N * sizeof(int2));
    int2* sbe   = (int2*)alloc((size_t)N * sizeof(int2));
    int* snode  = (int*)alloc((size_t)N * sizeof(int));
    float* W12  = (float*)alloc(128 * 64 * sizeof(float));
    float* Wc   = (float*)alloc(128 * 40 * sizeof(float));
    int* gcnt   = (int*)alloc(NBMAX * sizeof(int));
    int* dcnt   = (int*)alloc(DBINS * sizeof(int));
    int* dcur   = (int*)alloc(DBINS * sizeof(int));

    k_w12<<<(128 * 64 + 255) / 256, 256, 0, stream>>>(W1, W2, W12, gcnt, dcnt);
    k_wc<<<(128 * 40 + 255) / 256, 256, 0, stream>>>(W12, W3, Wc);

    int npart = (E + PCHUNK - 1) / PCHUNK;
    int ngemm = (N * 5 + 255) / 256;
    k_gp<<<npart + ngemm, 256, 0, stream>>>((const float4*)x, (const float4*)Wc,
                                            bufA, N, esrc, edst, gcnt, part,
                                            E, nb, npart);

    k_csr<<<nb, 256, 0, stream>>>(part, gcnt, offs2, ssort, dcnt, N);
    k_dscan<<<1, DBINS, 0, stream>>>(dcnt, dcur);
    k_dscat<<<(N + 1023) / 1024, 256, 0, stream>>>(offs2, dcur, sbe, snode, N);

    int nwaves = (N + NPW - 1) / NPW;
    int agg_grid = (nwaves + 3) / 4;   // 4 waves (256 threads) per block
    k_agg<0><<<agg_grid, 256, 0, stream>>>(bufA, bufB, sbe, snode, ssort, N);
    k_agg<0><<<agg_grid, 256, 0, stream>>>(bufB, bufA, sbe, snode, ssort, N);
    k_agg<1><<<agg_grid, 256, 0, stream>>>(bufA, out, sbe, snode, ssort, N);
}

// Round 18
// 164.984 us; speedup vs baseline: 1.0570x; 1.0570x over previous
//
#include <hip/hip_runtime.h>
#include <hip/hip_fp16.h>
#include <math.h>

// SGC: out = log_softmax( S^3 * x * (W1*W2*W3) )
// Pipeline: w12 -> wc -> FUSED{gemm || bucket-partition} -> bucket-local CSR
// -> 3x gather-agg (12 nodes/wave, 5-lane groups, uint4 f16 loads,
// v_pk_add_f16, 10-edge unroll w/ dual accumulator sets, pipelined indices).
// NOTE: all __shfl are executed UNCONDITIONALLY by all 64 lanes.
// Falsified alternatives (do not retry): plane-major layout (r12, +43µs),
// PCHUNK=16384 (r14, +16µs), degree-sorted items (r17, +9µs: scattered
// output writes + extra launches outweigh wave balance).

#define BW    128     // nodes per bucket
#define NBMAX 1024
#define BCAP  3072    // per-bucket capacity (avg 2046, +22 sigma slack)
#define D     40
#define RS    64      // padded row stride (f16 elems) = 128 B (one L2 line)
#define NPW   12      // nodes per wave in k_agg
#define PCHUNK 4096   // edges per partition block

typedef unsigned short u16;
typedef unsigned int   u32;

static __device__ inline u32 hadd2u(u32 a, u32 b) {
    __half2 ha = *(__half2*)&a, hb = *(__half2*)&b;
    __half2 r = __hadd2(ha, hb);
    return *(u32*)&r;
}

// ---------- weight collapse, multi-block ----------
// W12 = W1(128x64) @ W2(64x64); block 0 also zeroes gcnt
__global__ void k_w12(const float* __restrict__ W1, const float* __restrict__ W2,
                      float* __restrict__ W12, int* __restrict__ gcnt) {
    int idx = blockIdx.x * blockDim.x + threadIdx.x;
    if (blockIdx.x == 0) {
        for (int i = threadIdx.x; i < NBMAX; i += blockDim.x) gcnt[i] = 0;
    }
    if (idx >= 128 * 64) return;
    int r = idx >> 6, c = idx & 63;
    float acc = 0.f;
#pragma unroll
    for (int k = 0; k < 64; ++k) acc += W1[r * 64 + k] * W2[k * 64 + c];
    W12[idx] = acc;
}

// Wc = W12(128x64) @ W3(64x40)
__global__ void k_wc(const float* __restrict__ W12, const float* __restrict__ W3,
                     float* __restrict__ Wc) {
    int idx = blockIdx.x * blockDim.x + threadIdx.x;
    if (idx >= 128 * 40) return;
    int r = idx / 40, c = idx - r * 40;
    float acc = 0.f;
#pragma unroll
    for (int k = 0; k < 64; ++k) acc += W12[r * 64 + k] * W3[k * 40 + c];
    Wc[idx] = acc;
}

// ---------- FUSED: blocks [0,npart) partition edges; rest do the GEMM ------
__global__ void k_gp(const float4* __restrict__ x4, const float4* __restrict__ Wc4,
                     u16* __restrict__ yout, int n_nodes,
                     const int* __restrict__ src, const int* __restrict__ dst,
                     int* __restrict__ gcnt, int* __restrict__ part,
                     int E, int nb, int npart) {
    __shared__ union {
        struct { int h[NBMAX]; int base[NBMAX]; } p;
        float4 wc[1280];
    } sm;
    int t = threadIdx.x;

    if ((int)blockIdx.x < npart) {
        // ---------------- partition path ----------------
        int e0 = blockIdx.x * PCHUNK;
        int e1 = min(e0 + PCHUNK, E);
        for (int i = t; i < nb; i += 256) sm.p.h[i] = 0;
        __syncthreads();
        for (int e = e0 + t; e < e1; e += 1024) {
#pragma unroll
            for (int u = 0; u < 4; ++u) {
                int ee = e + u * 256;
                if (ee < e1) atomicAdd(&sm.p.h[dst[ee] >> 7], 1);
            }
        }
        __syncthreads();
        for (int i = t; i < nb; i += 256) {
            int c = sm.p.h[i];
            sm.p.base[i] = c ? atomicAdd(&gcnt[i], c) : 0;
        }
        __syncthreads();
        for (int i = t; i < nb; i += 256) sm.p.h[i] = 0;  // reuse as cursor
        __syncthreads();
        for (int eb = e0 + t; eb < e1; eb += 2048) {
            int dd[8], ss[8], pp[8];
#pragma unroll
            for (int u = 0; u < 8; ++u) {
                int e = eb + u * 256;
                bool v = e < e1;
                dd[u] = v ? dst[e] : 0;
                ss[u] = v ? src[e] : 0;
            }
#pragma unroll
            for (int u = 0; u < 8; ++u) {
                int e = eb + u * 256;
                int b = dd[u] >> 7;
                pp[u] = (e < e1) ? (sm.p.base[b] + atomicAdd(&sm.p.h[b], 1)) : BCAP;
            }
#pragma unroll
            for (int u = 0; u < 8; ++u) {
                int b = dd[u] >> 7;
                if (pp[u] < BCAP)
                    part[(size_t)b * BCAP + pp[u]] = (ss[u] << 7) | (dd[u] & 127);
            }
        }
    } else {
        // ---------------- gemm path ----------------
        for (int i = t; i < 1280; i += 256) sm.wc[i] = Wc4[i];
        __syncthreads();
        int tid = ((int)blockIdx.x - npart) * 256 + t;
        int node = tid / 5, j0 = tid - node * 5;
        if (node >= n_nodes) return;
        float4 a0 = {0.f, 0.f, 0.f, 0.f}, a1 = {0.f, 0.f, 0.f, 0.f};
        const float4* xr = x4 + (size_t)node * 32;
#pragma unroll
        for (int k4 = 0; k4 < 32; ++k4) {
            float4 v = xr[k4];
#pragma unroll
            for (int kk = 0; kk < 4; ++kk) {
                float c = (kk == 0) ? v.x : (kk == 1) ? v.y : (kk == 2) ? v.z : v.w;
                float4 w0 = sm.wc[(k4 * 4 + kk) * 10 + j0 * 2];
                float4 w1 = sm.wc[(k4 * 4 + kk) * 10 + j0 * 2 + 1];
                a0.x += c * w0.x; a0.y += c * w0.y; a0.z += c * w0.z; a0.w += c * w0.w;
                a1.x += c * w1.x; a1.y += c * w1.y; a1.z += c * w1.z; a1.w += c * w1.w;
            }
        }
        __half2 h0 = __floats2half2_rn(a0.x, a0.y);
        __half2 h1 = __floats2half2_rn(a0.z, a0.w);
        __half2 h2 = __floats2half2_rn(a1.x, a1.y);
        __half2 h3 = __floats2half2_rn(a1.z, a1.w);
        uint4 st;
        st.x = *(u32*)&h0; st.y = *(u32*)&h1; st.z = *(u32*)&h2; st.w = *(u32*)&h3;
        *(uint4*)(yout + (size_t)node * RS + j0 * 8) = st;
    }
}

// ---------- bucket-local CSR: offs2[n]=(beg,end), ssort grouped by dst ------
__global__ void k_csr(const int* __restrict__ part, const int* __restrict__ gcnt,
                      int2* __restrict__ offs2, int* __restrict__ ssort, int N) {
    __shared__ int cnt[BW];
    __shared__ int pos[BW];
    __shared__ int cur[BW];
    __shared__ int wsum[2];
    int b = blockIdx.x, t = threadIdx.x;
    int m = min(gcnt[b], BCAP);
    const int* bp = part + (size_t)b * BCAP;
    if (t < BW) cnt[t] = 0;
    __syncthreads();
    for (int k = t; k < m; k += 256)
        atomicAdd(&cnt[bp[k] & 127], 1);
    __syncthreads();
    int v = 0, inc = 0;
    if (t < BW) {
        v = cnt[t];
        inc = v;
#pragma unroll
        for (int off = 1; off < 64; off <<= 1) {
            int u = __shfl_up(inc, off, 64);
            if ((t & 63) >= off) inc += u;
        }
        if ((t & 63) == 63) wsum[t >> 6] = inc;
    }
    __syncthreads();
    int node0 = b * BW;
    if (t < BW) {
        int local = ((t >= 64) ? wsum[0] : 0) + inc - v;   // exclusive
        pos[t] = local;
        cur[t] = 0;
        if (node0 + t < N)
            offs2[node0 + t] = make_int2(b * BCAP + local, b * BCAP + local + v);
    }
    __syncthreads();
    for (int k = t; k < m; k += 256) {
        int p = bp[k];
        int r = p & 127;
        int loc = atomicAdd(&cur[r], 1);
        ssort[(size_t)b * BCAP + pos[r] + loc] = p >> 7;
    }
}

// ---------- aggregation: 12 nodes per wave, 5-lane group per node ----------
// 10-edge unroll: two 5-index register blocks (sv0, sv1), dual accumulator
// sets (c*, d*) so the two gather groups don't serialize through one f16
// add chain; next trip's index blocks prefetched while gathers in flight.
template <int FINAL>
__global__ void k_agg(const u16* __restrict__ yin, void* __restrict__ youtv,
                      const int2* __restrict__ offs2, const int* __restrict__ srcs,
                      int n_nodes) {
    int wid = (blockIdx.x * blockDim.x + threadIdx.x) >> 6;
    int lane = threadIdx.x & 63;
    int g = lane / 5;                 // 0..12 (lanes 60..63: g=12, idle)
    int sub = lane - g * 5;           // 0..4
    int node = wid * NPW + g;
    bool nv = (g < NPW) && (node < n_nodes);
    int2 be = offs2[nv ? node : 0];
    int beg = be.x;
    int deg = nv ? (be.y - be.x) : 0;
    u32 suboff = (u32)sub * 16u;      // byte offset within 128B row
    u32 c0 = 0, c1 = 0, c2 = 0, c3 = 0;   // accumulator set A
    u32 d0 = 0, d1 = 0, d2 = 0, d3 = 0;   // accumulator set B
    // wave-uniform max degree (one-time)
    int mdeg = deg;
#pragma unroll
    for (int off = 1; off < 64; off <<= 1)
        mdeg = max(mdeg, __shfl_xor(mdeg, off, 64));
    // prologue: index blocks for k=0..9
    int sv0 = (sub < deg) ? srcs[beg + sub] : 0;
    int sv1 = (5 + sub < deg) ? srcs[beg + 5 + sub] : 0;
    for (int k = 0; k < mdeg; k += 10) {
        int kn = k + 10;
        int svn0 = (kn + sub < deg) ? srcs[beg + kn + sub] : 0;
        int svn1 = (kn + 5 + sub < deg) ? srcs[beg + kn + 5 + sub] : 0;
#pragma unroll
        for (int j = 0; j < 5; ++j) {
            int s = __shfl(sv0, g * 5 + j, 64);   // ALL lanes execute
            if (k + j < deg) {
                uint4 w = *(const uint4*)((const char*)yin +
                              (size_t)(((u32)s << 7) + suboff));
                c0 = hadd2u(c0, w.x); c1 = hadd2u(c1, w.y);
                c2 = hadd2u(c2, w.z); c3 = hadd2u(c3, w.w);
            }
        }
#pragma unroll
        for (int j = 0; j < 5; ++j) {
            int s = __shfl(sv1, g * 5 + j, 64);   // ALL lanes execute
            if (k + 5 + j < deg) {
                uint4 w = *(const uint4*)((const char*)yin +
                              (size_t)(((u32)s << 7) + suboff));
                d0 = hadd2u(d0, w.x); d1 = hadd2u(d1, w.y);
                d2 = hadd2u(d2, w.z); d3 = hadd2u(d3, w.w);
            }
        }
        sv0 = svn0; sv1 = svn1;
    }
    c0 = hadd2u(c0, d0); c1 = hadd2u(c1, d1);
    c2 = hadd2u(c2, d2); c3 = hadd2u(c3, d3);
    if (FINAL) {
        float2 f0 = __half22float2(*(__half2*)&c0);
        float2 f1 = __half22float2(*(__half2*)&c1);
        float2 f2 = __half22float2(*(__half2*)&c2);
        float2 f3 = __half22float2(*(__half2*)&c3);
        // group-local (5-lane) reduce: rotate +1,+2 on partials, +4 on orig
        int s1 = sub + 1; s1 = (s1 >= 5) ? s1 - 5 : s1;
        int s2 = sub + 2; s2 = (s2 >= 5) ? s2 - 5 : s2;
        int s4 = sub + 4; s4 = (s4 >= 5) ? s4 - 5 : s4;
        int r1 = g * 5 + s1, r2 = g * 5 + s2, r4 = g * 5 + s4;
        float m0 = fmaxf(fmaxf(fmaxf(f0.x, f0.y), fmaxf(f1.x, f1.y)),
                         fmaxf(fmaxf(f2.x, f2.y), fmaxf(f3.x, f3.y)));
        float m = fmaxf(m0, __shfl(m0, r1, 64));        // window 2
        m = fmaxf(m, __shfl(m, r2, 64));                // window 4
        m = fmaxf(m, __shfl(m0, r4, 64));               // + elem at +4
        float e0 = __expf(f0.x - m) + __expf(f0.y - m) + __expf(f1.x - m) +
                   __expf(f1.y - m) + __expf(f2.x - m) + __expf(f2.y - m) +
                   __expf(f3.x - m) + __expf(f3.y - m);
        float sm = e0 + __shfl(e0, r1, 64);             // window 2
        sm = sm + __shfl(sm, r2, 64);                   // window 4
        sm = sm + __shfl(e0, r4, 64);                   // + elem at +4
        float ls = __logf(sm) + m;
        if (nv) {
            float4 o1 = {f0.x - ls, f0.y - ls, f1.x - ls, f1.y - ls};
            float4 o2 = {f2.x - ls, f2.y - ls, f3.x - ls, f3.y - ls};
            float* op = (float*)youtv + (size_t)node * D + sub * 8;
            *(float4*)op = o1;
            *(float4*)(op + 4) = o2;
        }
    } else {
        if (nv) {
            uint4 st = {c0, c1, c2, c3};
            *(uint4*)((u16*)youtv + (size_t)node * RS + sub * 8) = st;
        }
    }
}

extern "C" void kernel_launch(void* const* d_in, const int* in_sizes, int n_in,
                              void* d_out, int out_size, void* d_ws, size_t ws_size,
                              hipStream_t stream) {
    const float* x   = (const float*)d_in[0];
    const int* esrc  = (const int*)d_in[1];
    const int* edst  = (const int*)d_in[2];
    const float* W1  = (const float*)d_in[3];
    const float* W2  = (const float*)d_in[4];
    const float* W3  = (const float*)d_in[5];
    int N = in_sizes[0] / 128;
    int E = in_sizes[1];
    float* out = (float*)d_out;

    int nb = (N + BW - 1) / BW;

    char* ws = (char*)d_ws;
    auto alloc = [&](size_t bytes) {
        char* p = ws;
        ws += (bytes + 255) & ~(size_t)255;
        return p;
    };
    u16* bufA   = (u16*)alloc((size_t)N * RS * sizeof(u16));        // 12.8 MB
    u16* bufB   = (u16*)alloc((size_t)N * RS * sizeof(u16));        // 12.8 MB
    int* part   = (int*)bufB;   // alias: part dead before bufB first written
    int* ssort  = (int*)alloc((size_t)nb * BCAP * sizeof(int));     // 9.6 MB
    int2* offs2 = (int2*)alloc((size_t)N * sizeof(int2));
    float* W12  = (float*)alloc(128 * 64 * sizeof(float));
    float* Wc   = (float*)alloc(128 * 40 * sizeof(float));
    int* gcnt   = (int*)alloc(NBMAX * sizeof(int));

    k_w12<<<(128 * 64 + 255) / 256, 256, 0, stream>>>(W1, W2, W12, gcnt);
    k_wc<<<(128 * 40 + 255) / 256, 256, 0, stream>>>(W12, W3, Wc);

    int npart = (E + PCHUNK - 1) / PCHUNK;
    int ngemm = (N * 5 + 255) / 256;
    k_gp<<<npart + ngemm, 256, 0, stream>>>((const float4*)x, (const float4*)Wc,
                                            bufA, N, esrc, edst, gcnt, part,
                                            E, nb, npart);

    k_csr<<<nb, 256, 0, stream>>>(part, gcnt, offs2, ssort, N);

    int nwaves = (N + NPW - 1) / NPW;
    int agg_grid = (nwaves + 3) / 4;   // 4 waves (256 threads) per block
    k_agg<0><<<agg_grid, 256, 0, stream>>>(bufA, bufB, offs2, ssort, N);
    k_agg<0><<<agg_grid, 256, 0, stream>>>(bufB, bufA, offs2, ssort, N);
    k_agg<1><<<agg_grid, 256, 0, stream>>>(bufA, out, offs2, ssort, N);
}